// Round 12
// baseline (1964.522 us; speedup 1.0000x reference)
//
#include <hip/hip_runtime.h>
#include <math.h>

#define NN    325
#define BB    64
#define TT    12
#define NODE  4096          // per-node stride of fp32 h/uu buffers: [n][c<64][b<64]
#define KD    352           // padded k-dim (nodes), 11*32
#define NPADR 384           // padded Scomb rows per matrix (24 tiles of 16)
#define XP    360           // LDS pitch (wg kernel)
#define XP2   200           // LDS pitch (diff chunk tile)
#define XW0   192           // diff K-chunk 0 width
#define XW1   160           // diff K-chunk 1 width
#define OBP   72            // out-stage pitch (ushorts)
#define KP0   352           // mats kk count, layer 0 (5*65=325 used)
#define KP1   640           // mats kk count, layer 1 (5*128)
#define SB2   512           // setup2 grid
// mats layout (kk-major): mats[(kk*NN + n)*64 + b]
// diff LDS swizzle: element (row,col) stored at col ^ (((row>>3)&7)<<3)

typedef unsigned short ushort;
typedef __attribute__((ext_vector_type(8))) short short8v;
typedef __attribute__((ext_vector_type(4))) short short4v;
typedef __attribute__((ext_vector_type(4))) float float4v;

static __device__ __forceinline__ ushort f2bf(float f){
  unsigned u = __builtin_bit_cast(unsigned, f);
  u += 0x7fffu + ((u >> 16) & 1u);          // RNE
  return (ushort)(u >> 16);
}

// ---------------------------------------------------------------- setup ----
__global__ void k_sums(const float* __restrict__ adj, float* __restrict__ rs,
                       float* __restrict__ cs){
  __shared__ float red[8];
  int j = blockIdx.x;
  int tid = threadIdx.x, gq = tid >> 6;
  float rv = 0.f, cv = 0.f;
  for (int k = tid; k < NN; k += 256){
    rv += adj[j*NN + k];
    cv += adj[k*NN + j];
  }
  #pragma unroll
  for (int o = 32; o > 0; o >>= 1){
    rv += __shfl_down(rv, o);
    cv += __shfl_down(cv, o);
  }
  if ((tid & 63) == 0){ red[gq] = rv; red[4 + gq] = cv; }
  __syncthreads();
  if (tid == 0){
    rs[j] = red[0]+red[1]+red[2]+red[3];
    cs[j] = red[4]+red[5]+red[6]+red[7];
  }
}

// merged: Sfp + Scomb slots 0,2 + Wt transposes + h/mats init
__global__ void k_setup2(const float* __restrict__ adj, const float* __restrict__ rs,
                         const float* __restrict__ cs, const float* __restrict__ inp,
                         const float* __restrict__ init,
                         const float* __restrict__ Wg0, const float* __restrict__ Wc0,
                         const float* __restrict__ Wg1, const float* __restrict__ Wc1,
                         float* __restrict__ Sfp, ushort* __restrict__ Scomb,
                         ushort* __restrict__ Wg0t, ushort* __restrict__ Wc0t,
                         ushort* __restrict__ Wg1t, ushort* __restrict__ Wc1t,
                         float* __restrict__ h0, float* __restrict__ h1,
                         ushort* __restrict__ matsL0, ushort* __restrict__ matsL1){
  int bx = blockIdx.x, t = threadIdx.x;
  if (bx < NN){                       // init task: node bx
    int n = bx, b = t & 63, cq = t >> 6;
    #pragma unroll
    for (int ii = 0; ii < 16; ++ii){
      int c = cq*16 + ii;
      float h0v = init[(size_t)(b*NN + n)*64 + c];
      float h1v = init[(size_t)BB*NN*64 + (size_t)(b*NN + n)*64 + c];
      h0[(size_t)n*NODE + c*64 + b] = h0v;
      h1[(size_t)n*NODE + c*64 + b] = h1v;
      matsL0[((size_t)(1 + c)*NN + n)*64 + b]  = f2bf(h0v);
      matsL1[((size_t)c*NN + n)*64 + b]        = f2bf(h0v);
      matsL1[((size_t)(64 + c)*NN + n)*64 + b] = f2bf(h1v);
    }
    if (t < 64)
      matsL0[(size_t)n*64 + t] = f2bf(inp[(size_t)t*NN + n]);
  }
  for (int idx = bx*256 + t; idx < 2*NN*NN; idx += SB2*256){
    int s = idx / (NN*NN), rem = idx - s*(NN*NN);
    int i = rem / NN, j = rem - i*NN;
    float v = s ? adj[i*NN + j]/cs[j] : adj[j*NN + i]/rs[j];
    Sfp[idx] = v;
    Scomb[(size_t)(2*s)*NPADR*KD + (size_t)i*KD + j] = f2bf(v);
  }
  // Wt[o][k], k = m*C + c, from W[(c*5+m)*O + o]; zero for k >= 5C
  {
    const float* Ws[4] = { Wg0, Wc0, Wg1, Wc1 };
    ushort* Wts[4]     = { Wg0t, Wc0t, Wg1t, Wc1t };
    const int Cs[4] = { 65, 65, 128, 128 };
    const int Os[4] = { 128, 64, 128, 64 };
    const int Kp[4] = { KP0, KP0, KP1, KP1 };
    for (int q = 0; q < 4; ++q){
      int total = Os[q]*Kp[q];
      for (int idx = bx*256 + t; idx < total; idx += SB2*256){
        int o = idx / Kp[q], k = idx - o*Kp[q];
        int m = k / Cs[q], c = k - m*Cs[q];
        Wts[q][idx] = f2bf(m < 5 ? Ws[q][(c*5 + m)*Os[q] + o] : 0.f);
      }
    }
  }
}

// Scomb slots 1,3 = 2*S_s^2 - I via MFMA (A = Scomb slot 2s bf16, X staged from Sfp)
__global__ __launch_bounds__(256) void k_s2(const float* __restrict__ Sfp,
                                            ushort* __restrict__ Scomb){
  __shared__ ushort X[64][XP];
  int jt = blockIdx.x, rh2 = blockIdx.y, s = blockIdx.z;
  int t = threadIdx.x, w = t >> 6, r = t & 15, g = (t >> 4) & 3;
  const float* S = Sfp + (size_t)s*NN*NN;
  for (int idx = t; idx < KD*8; idx += 256){
    int k = idx >> 3, j0 = (idx & 7)*8;
    #pragma unroll
    for (int i = 0; i < 8; ++i){
      int j = j0 + i, col = jt*64 + j;
      float v = (k < NN && col < NN) ? S[(size_t)k*NN + col] : 0.f;
      X[j][k] = f2bf(v);
    }
  }
  __syncthreads();
  const ushort* A = Scomb + (size_t)(2*s)*NPADR*KD + (size_t)(rh2*192)*KD;
  float4v acc[3][4];
  #pragma unroll
  for (int i = 0; i < 3; ++i)
    #pragma unroll
    for (int q = 0; q < 4; ++q) acc[i][q] = (float4v){0.f,0.f,0.f,0.f};
  for (int kc = 0; kc < KD/32; ++kc){
    short8v a[3], bbv[4];
    #pragma unroll
    for (int mt = 0; mt < 3; ++mt)
      a[mt] = *(const short8v*)&A[(size_t)((w*3 + mt)*16 + r)*KD + kc*32 + g*8];
    #pragma unroll
    for (int nt = 0; nt < 4; ++nt)
      bbv[nt] = *(const short8v*)&X[nt*16 + r][kc*32 + g*8];
    #pragma unroll
    for (int mt = 0; mt < 3; ++mt)
      #pragma unroll
      for (int nt = 0; nt < 4; ++nt)
        acc[mt][nt] = __builtin_amdgcn_mfma_f32_16x16x32_bf16(a[mt], bbv[nt], acc[mt][nt], 0, 0, 0);
  }
  ushort* dst = Scomb + (size_t)(2*s + 1)*NPADR*KD;
  #pragma unroll
  for (int mt = 0; mt < 3; ++mt){
    int node0 = rh2*192 + (w*3 + mt)*16 + g*4;
    #pragma unroll
    for (int nt = 0; nt < 4; ++nt){
      int col = nt*16 + r, jg = jt*64 + col;
      #pragma unroll
      for (int i = 0; i < 4; ++i){
        int n = node0 + i;
        if (n < NN && jg < NN)
          dst[(size_t)n*KD + jg] = f2bf(2.f*acc[mt][nt][i] - (n == jg ? 1.f : 0.f));
      }
    }
  }
}

// ----------------------------------------------- multi-segment diffusion ----
struct Seg {
  const ushort* sm;      // mats source channel base (or null -> sf)
  const float*  sf;      // fp32 [b*NN + n] source (x channel); also writes slot 0
  ushort* dm;
  int C, cs0, cd0;
};
struct DiffA {
  const ushort* Sc;
  Seg seg[3];
  int e0, e1, nch;       // seg0: [0,e0), seg1: [e0,e1), seg2: [e1,nch)
};

// 1D grid, XCD-aware decomposition: lin = (cu/8)*64 + sub*8 + (cu%8).
// All 8 sub-blocks (y=sub>>2, m=sub&3) of channel cu share lin%8 -> same XCD.
// K-chunked X tile (2 chunks: 192+160) halves LDS -> ~5 blocks/CU.
__global__ __launch_bounds__(256, 5) void k_diffN(DiffA da){
  __shared__ ushort X[64][XP2];                    // 25.6 KB
  ushort (*OB)[OBP] = (ushort (*)[OBP])&X[0][0];   // 96-row out-stage overlay
  int lin = blockIdx.x;
  int cu = (lin >> 6)*8 + (lin & 7);
  if (cu >= da.nch) return;
  int sub = (lin >> 3) & 7;
  const int y = sub >> 2, m = sub & 3;
  Seg sg; int u;
  if (cu < da.e0){ sg = da.seg[0]; u = cu; }
  else if (cu < da.e1){ sg = da.seg[1]; u = cu - da.e0; }
  else { sg = da.seg[2]; u = cu - da.e1; }
  int t = threadIdx.x, w = t >> 6;
  int r = t & 15, g = (t >> 4) & 3;

  const ushort* S = da.Sc + ((size_t)m*NPADR + (size_t)y*192)*KD;
  float4v acc[3][4];
  #pragma unroll
  for (int i = 0; i < 3; ++i)
    #pragma unroll
    for (int q = 0; q < 4; ++q) acc[i][q] = (float4v){0.f,0.f,0.f,0.f};

  int swr[4];
  #pragma unroll
  for (int nt = 0; nt < 4; ++nt)
    swr[nt] = (((nt*16 + r) >> 3) & 7) << 3;       // read-side swizzle per nt

  #pragma unroll
  for (int ch = 0; ch < 2; ++ch){
    const int koff = ch ? XW0 : 0;
    const int NKC  = ch ? (XW1/32) : (XW0/32);     // 5 : 6
    if (ch) __syncthreads();                       // prior chunk reads done
    if (sg.sm){
      // vector stage: 16B loads (8 lines per wave-instr), swizzled scatter
      const ushort* src = sg.sm + (size_t)(sg.cs0 + u)*NN*64;
      int nb = t >> 3, b0 = (t & 7)*8;
      int s3 = (t & 7) << 3;                       // ((b0+i)>>3)&7 == t&7
      const short8v vz = {0,0,0,0,0,0,0,0};
      short8v v[6];
      #pragma unroll
      for (int j = 0; j < 6; ++j){
        if (j >= NKC) break;
        int n = koff + j*32 + nb;
        v[j] = (n < NN) ? *(const short8v*)&src[(size_t)n*64 + b0] : vz;
      }
      #pragma unroll
      for (int j = 0; j < 6; ++j){
        if (j >= NKC) break;
        int col = (j*32 + nb) ^ s3;
        #pragma unroll
        for (int i = 0; i < 8; ++i) X[b0 + i][col] = (ushort)v[j][i];
      }
    } else {
      // fp32 x channel: scalar loads + slot-0 writeback; swizzled LDS writes
      const int W4 = ch ? (XW1/4) : (XW0/4);       // 40 : 48
      const int NG = 64*W4;
      for (int idx = t; idx < NG; idx += 256){
        int b = idx / W4, n4 = (idx - b*W4)*4;
        int s3 = ((b >> 3) & 7) << 3;
        ushort us[4];
        #pragma unroll
        for (int i = 0; i < 4; ++i){
          int n = koff + n4 + i;
          us[i] = (n < NN) ? f2bf(sg.sf[(size_t)b*NN + n]) : (ushort)0;
        }
        short4v pk; pk[0]=(short)us[0]; pk[1]=(short)us[1]; pk[2]=(short)us[2]; pk[3]=(short)us[3];
        *(short4v*)&X[b][n4 ^ s3] = pk;
        #pragma unroll
        for (int i = 0; i < 4; ++i){
          int n = koff + n4 + i;
          if (n < NN) sg.dm[(size_t)n*64 + b] = us[i];
        }
      }
    }
    __syncthreads();
    for (int kc = 0; kc < NKC; ++kc){
      short8v a[3], bbv[4];
      #pragma unroll
      for (int mt = 0; mt < 3; ++mt)
        a[mt] = *(const short8v*)&S[(size_t)((w*3 + mt)*16 + r)*KD + koff + kc*32 + g*8];
      #pragma unroll
      for (int nt = 0; nt < 4; ++nt)
        bbv[nt] = *(const short8v*)&X[nt*16 + r][(kc*32 + g*8) ^ swr[nt]];
      #pragma unroll
      for (int mt = 0; mt < 3; ++mt)
        #pragma unroll
        for (int nt = 0; nt < 4; ++nt)
          acc[mt][nt] = __builtin_amdgcn_mfma_f32_16x16x32_bf16(a[mt], bbv[nt], acc[mt][nt], 0, 0, 0);
    }
  }

  __syncthreads();                        // all X reads done -> reuse as OB
  // out-stage + copy-out in two 96-row halves
  ushort* dst = sg.dm + (size_t)((1 + m)*sg.C + sg.cd0 + u)*NN*64;
  int n0 = y*192;
  #pragma unroll
  for (int half = 0; half < 2; ++half){
    if ((w >> 1) == half){
      #pragma unroll
      for (int mt = 0; mt < 3; ++mt){
        int lr0 = (w*3 + mt)*16 + g*4 - half*96;
        #pragma unroll
        for (int nt = 0; nt < 4; ++nt){
          int col = nt*16 + r;
          #pragma unroll
          for (int i = 0; i < 4; ++i)
            OB[lr0 + i][col] = f2bf(acc[mt][nt][i]);
        }
      }
    }
    __syncthreads();
    {
      int lr = t >> 3, q = (t & 7)*8;
      #pragma unroll
      for (int it = 0; it < 3; ++it){
        int row = it*32 + lr;
        int n = n0 + half*96 + row;
        if (n < NN)
          *(short8v*)&dst[(size_t)n*64 + q] = *(short8v*)&OB[row][q];
      }
    }
    if (half == 0) __syncthreads();       // before overwriting OB
  }
}

// ------------------------------------------- dual-descriptor W-GEMM (MFMA) ----
struct WgD {
  const ushort* mats; const ushort* Wt; const float* bias;
  float* h; float* uu;
  ushort* dstA; ushort* dstB;         // kk-major slot bases (dstB may be null)
  const float* Wfc; const float* bfc; float* outp;
  const float* xnext; ushort* xdst;   // optional next-x stage (MODE 1)
  int KPAD; int MODE;      // MODE 0: gate (o-tile = oy*64); 1: cand (h-update)
};

template<int KPAD>
static __device__ __forceinline__ void wg_body(
    const WgD& d, int n, int oy, ushort (*XT)[XP], float* fcbuf)
{
  constexpr int NST = (KPAD > 352) ? 2 : 1;
  constexpr int KH  = (KPAD > 352) ? 320 : KPAD;
  constexpr int NCH = KH/32;
  int t = threadIdx.x, w = t >> 6;
  int r = t & 15, g = (t >> 4) & 3;
  const bool fc = (d.MODE == 1) && (d.outp != nullptr);
  if (fc && t < 64) fcbuf[t] = 0.f;

  float4v acc[4];
  #pragma unroll
  for (int nt = 0; nt < 4; ++nt) acc[nt] = (float4v){0.f,0.f,0.f,0.f};

  int kk0 = t >> 3, b0 = (t & 7)*8;
  int swz = (t & 3) << 3;
  int swr[4];
  #pragma unroll
  for (int nt = 0; nt < 4; ++nt)
    swr[nt] = ((nt*2 + (r >> 3)) & 3) << 3;
  #pragma unroll
  for (int st = 0; st < NST; ++st){
    int kbase = st*KH;
    if (st) __syncthreads();
    short8v v[NCH];
    #pragma unroll
    for (int j = 0; j < NCH; ++j)
      v[j] = *(const short8v*)&d.mats[((size_t)(kbase + j*32 + kk0)*NN + n)*64 + b0];
    #pragma unroll
    for (int j = 0; j < NCH; ++j){
      int col = (j*32 + kk0) ^ swz;
      #pragma unroll
      for (int i = 0; i < 8; ++i) XT[b0 + i][col] = (ushort)v[j][i];
    }
    __syncthreads();
    for (int kc = 0; kc < NCH; ++kc){
      short8v a0 = *(const short8v*)&d.Wt[(size_t)(oy*64 + w*16 + r)*KPAD + kbase + kc*32 + g*8];
      short8v bbv[4];
      #pragma unroll
      for (int nt = 0; nt < 4; ++nt)
        bbv[nt] = *(const short8v*)&XT[nt*16 + r][(kc*32 + g*8) ^ swr[nt]];
      #pragma unroll
      for (int nt = 0; nt < 4; ++nt)
        acc[nt] = __builtin_amdgcn_mfma_f32_16x16x32_bf16(a0, bbv[nt], acc[nt], 0, 0, 0);
    }
  }

  __syncthreads();                        // all XT reads done; reuse as out stage
  #pragma unroll
  for (int nt = 0; nt < 4; ++nt){
    int b2 = nt*16 + r;
    float p = 0.f;
    #pragma unroll
    for (int i = 0; i < 4; ++i){
      int o = w*16 + g*4 + i;             // within o-tile
      float vv = acc[nt][i] + d.bias[oy*64 + o];
      if (d.MODE == 0){
        float sg = 1.f/(1.f + expf(-vv));
        if (oy == 0) XT[o][b2] = f2bf(sg * d.h[(size_t)n*NODE + o*64 + b2]);
        else         d.uu[(size_t)n*NODE + o*64 + b2] = sg;
      } else {
        float cv = tanhf(vv);
        size_t idx = (size_t)n*NODE + o*64 + b2;
        float uv = d.uu[idx];
        float hn = uv*d.h[idx] + (1.f - uv)*cv;
        d.h[idx] = hn;
        XT[o][b2] = f2bf(hn);
        if (fc) p += hn * d.Wfc[o];
      }
    }
    if (fc) atomicAdd(&fcbuf[b2], p);
  }
  __syncthreads();
  if (d.MODE == 1 || oy == 0){             // coalesced copy-out of 64 kk-lines
    int o = t >> 2, q = (t & 3)*16;
    short8v v0 = *(short8v*)&XT[o][q];
    short8v v1 = *(short8v*)&XT[o][q + 8];
    ushort* dl = d.dstA + ((size_t)o*NN + n)*64 + q;
    *(short8v*)&dl[0] = v0;
    *(short8v*)&dl[8] = v1;
    if (d.dstB){
      ushort* dl2 = d.dstB + ((size_t)o*NN + n)*64 + q;
      *(short8v*)&dl2[0] = v0;
      *(short8v*)&dl2[8] = v1;
    }
  }
  if (d.MODE == 1){
    if (d.xnext && t < 64)
      d.xdst[(size_t)n*64 + t] = f2bf(d.xnext[(size_t)t*NN + n]);
    if (fc && t < 64)
      d.outp[(size_t)t*NN + n] = fcbuf[t] + d.bfc[0];
  }
}

__global__ __launch_bounds__(256) void k_wg2(WgD d0, int n0, WgD d1){
  __shared__ ushort XT[64][XP];
  __shared__ float fcbuf[64];
  const bool first = (blockIdx.x < (unsigned)n0);
  WgD d = first ? d0 : d1;
  int n = first ? blockIdx.x : blockIdx.x - n0;
  int oy = blockIdx.y;
  if (d.MODE == 1 && oy) return;           // block-uniform early exit
  if (d.KPAD == 352) wg_body<352>(d, n, oy, XT, fcbuf);
  else               wg_body<640>(d, n, oy, XT, fcbuf);
}

// ----------------------------------------------------------------- host ----
extern "C" void kernel_launch(void* const* d_in, const int* in_sizes, int n_in,
                              void* d_out, int out_size, void* d_ws, size_t ws_size,
                              hipStream_t stream){
  const float* inp  = (const float*)d_in[0];
  const float* init = (const float*)d_in[1];
  const float* adj  = (const float*)d_in[2];
  const float* Wg0  = (const float*)d_in[3];
  const float* bg0  = (const float*)d_in[4];
  const float* Wc0  = (const float*)d_in[5];
  const float* bc0  = (const float*)d_in[6];
  const float* Wg1  = (const float*)d_in[7];
  const float* bg1  = (const float*)d_in[8];
  const float* Wc1  = (const float*)d_in[9];
  const float* bc1  = (const float*)d_in[10];
  const float* Wfc  = (const float*)d_in[11];
  const float* bfc  = (const float*)d_in[12];
  (void)in_sizes; (void)n_in; (void)out_size; (void)ws_size;

  char* p = (char*)d_ws;
  auto alloc = [&](size_t bytes) -> void* {
    void* q = (void*)p; p += (bytes + 255) & ~(size_t)255; return q;
  };
  ushort* Scomb  = (ushort*)alloc((size_t)4*NPADR*KD*2);
  float*  Sfp    = (float*)alloc((size_t)2*NN*NN*4);
  ushort* Wg0t   = (ushort*)alloc((size_t)128*KP0*2);
  ushort* Wc0t   = (ushort*)alloc((size_t)64*KP0*2);
  ushort* Wg1t   = (ushort*)alloc((size_t)128*KP1*2);
  ushort* Wc1t   = (ushort*)alloc((size_t)64*KP1*2);
  float*  rs     = (float*)alloc(512*4);
  float*  cs     = (float*)alloc(512*4);
  float*  h0     = (float*)alloc((size_t)NN*NODE*4);
  float*  h1     = (float*)alloc((size_t)NN*NODE*4);
  float*  uu0    = (float*)alloc((size_t)NN*NODE*4);
  float*  uu1    = (float*)alloc((size_t)NN*NODE*4);
  ushort* matsL0 = (ushort*)alloc((size_t)KP0*NN*64*2);
  ushort* matsL1 = (ushort*)alloc((size_t)KP1*NN*64*2);
  float* out = (float*)d_out;

  hipMemsetAsync(out, 0, (size_t)BB*NN*4, stream);
  hipMemsetAsync(matsL0 + (size_t)325*NN*64, 0, (size_t)(KP0 - 325)*NN*64*2, stream);
  hipMemsetAsync(Scomb, 0, (size_t)4*NPADR*KD*2, stream);

  k_sums<<<NN, 256, 0, stream>>>(adj, rs, cs);
  k_setup2<<<SB2, 256, 0, stream>>>(adj, rs, cs, inp, init, Wg0, Wc0, Wg1, Wc1,
                                    Sfp, Scomb, Wg0t, Wc0t, Wg1t, Wc1t,
                                    h0, h1, matsL0, matsL1);
  k_s2<<<dim3(6, 2, 2), 256, 0, stream>>>(Sfp, Scomb);

  Seg segL0g  = { matsL0, nullptr, matsL0, 65, 0, 0 };      // full gate L0 (65 ch)
  Seg segL0c  = { matsL0, nullptr, matsL0, 65, 1, 1 };      // rh / h0 (64 ch)
  Seg segL1h1 = { matsL1, nullptr, matsL1, 128, 64, 64 };   // h1 / rh1 (64 ch)
  Seg segL1h0 = { matsL1, nullptr, matsL1, 128, 0, 0 };     // h0-part (64 ch)

  auto diffGrid = [](int nch){ return ((nch + 7)/8)*64; };

  // priming: full L0-gate diffusion (x_0 + h0)
  { DiffA da = { Scomb, { segL0g, segL0g, segL0g }, 65, 65, 65 };
    k_diffN<<<diffGrid(65), 256, 0, stream>>>(da); }

  WgD wg_g0 = { matsL0, Wg0t, bg0, h0, uu0, matsL0 + (size_t)1*NN*64, nullptr,
                nullptr, nullptr, nullptr, nullptr, nullptr, KP0, 0 };
  WgD wg_c0 = { matsL0, Wc0t, bc0, h0, uu0, matsL0 + (size_t)1*NN*64, matsL1,
                nullptr, nullptr, nullptr, nullptr, nullptr, KP0, 1 };
  WgD wg_g1 = { matsL1, Wg1t, bg1, h1, uu1, matsL1 + (size_t)64*NN*64, nullptr,
                nullptr, nullptr, nullptr, nullptr, nullptr, KP1, 0 };

  k_wg2<<<dim3(NN, 2), 256, 0, stream>>>(wg_g0, NN, wg_g0);   // wg L0-gate, t=0

  for (int t = 0; t < TT; ++t){
    // P2: L0-cand diff (rh) + L1-gate diff h1-part
    { DiffA da = { Scomb, { segL0c, segL1h1, segL0c }, 64, 128, 128 };
      k_diffN<<<diffGrid(128), 256, 0, stream>>>(da); }
    // P3: wg L0-cand -> h0_new
    k_wg2<<<dim3(NN, 1), 256, 0, stream>>>(wg_c0, NN, wg_c0);
    // P4: L1-gate diff h0-part + next-L0-gate diff h0-part + x_{t+1} channel
    { Seg segX = { nullptr, inp + (size_t)(t + 1)*BB*NN, matsL0, 65, 0, 0 };
      DiffA da = { Scomb, { segL1h0, segL0c, segX }, 64, 128, 129 };
      k_diffN<<<diffGrid(129), 256, 0, stream>>>(da); }
    // P5: wg L1-gate -> rh1 + uu1
    k_wg2<<<dim3(NN, 2), 256, 0, stream>>>(wg_g1, NN, wg_g1);
    // P6: L1-cand diff (rh1)
    { DiffA da = { Scomb, { segL1h1, segL1h1, segL1h1 }, 64, 64, 64 };
      k_diffN<<<diffGrid(64), 256, 0, stream>>>(da); }
    // P7: wg L1-cand (+fc)  [merged with next step's wg L0-gate]
    WgD wg_c1 = { matsL1, Wc1t, bc1, h1, uu1, matsL1 + (size_t)64*NN*64, nullptr,
                  Wfc, bfc, out + (size_t)(t + 1)*BB*NN,
                  (t + 1 < TT) ? inp + (size_t)(t + 1)*BB*NN : nullptr, matsL0,
                  KP1, 1 };
    if (t < TT - 1)
      k_wg2<<<dim3(2*NN, 2), 256, 0, stream>>>(wg_c1, NN, wg_g0);
    else
      k_wg2<<<dim3(NN, 1), 256, 0, stream>>>(wg_c1, NN, wg_c1);
  }
}

// Round 13
// 1481.473 us; speedup vs baseline: 1.3261x; 1.3261x over previous
//
#include <hip/hip_runtime.h>
#include <math.h>

#define NN    325
#define BB    64
#define TT    12
#define NODE  4096          // per-node stride of fp32 h/uu buffers: [n][c<64][b<64]
#define KD    352           // padded k-dim (nodes), 11*32
#define NPADR 384           // padded Scomb rows per matrix (24 tiles of 16)
#define XP    360           // LDS pitch
#define OBP   72            // out-stage pitch (ushorts)
#define KP0   352           // mats kk count, layer 0 (5*65=325 used)
#define KP1   640           // mats kk count, layer 1 (5*128)
#define SB2   512           // setup2 grid
// mats layout (kk-major): mats[(kk*NN + n)*64 + b], kk = m*C + c

typedef unsigned short ushort;
typedef __attribute__((ext_vector_type(8))) short short8v;
typedef __attribute__((ext_vector_type(4))) short short4v;
typedef __attribute__((ext_vector_type(4))) float float4v;

static __device__ __forceinline__ ushort f2bf(float f){
  unsigned u = __builtin_bit_cast(unsigned, f);
  u += 0x7fffu + ((u >> 16) & 1u);          // RNE
  return (ushort)(u >> 16);
}

// ---------------------------------------------------------------- setup ----
__global__ void k_sums(const float* __restrict__ adj, float* __restrict__ rs,
                       float* __restrict__ cs){
  __shared__ float red[8];
  int j = blockIdx.x;
  int tid = threadIdx.x, gq = tid >> 6;
  float rv = 0.f, cv = 0.f;
  for (int k = tid; k < NN; k += 256){
    rv += adj[j*NN + k];
    cv += adj[k*NN + j];
  }
  #pragma unroll
  for (int o = 32; o > 0; o >>= 1){
    rv += __shfl_down(rv, o);
    cv += __shfl_down(cv, o);
  }
  if ((tid & 63) == 0){ red[gq] = rv; red[4 + gq] = cv; }
  __syncthreads();
  if (tid == 0){
    rs[j] = red[0]+red[1]+red[2]+red[3];
    cs[j] = red[4]+red[5]+red[6]+red[7];
  }
}

// merged: Sfp + Scomb slots 0,2 + Wt transposes + h/mats init
__global__ void k_setup2(const float* __restrict__ adj, const float* __restrict__ rs,
                         const float* __restrict__ cs, const float* __restrict__ inp,
                         const float* __restrict__ init,
                         const float* __restrict__ Wg0, const float* __restrict__ Wc0,
                         const float* __restrict__ Wg1, const float* __restrict__ Wc1,
                         float* __restrict__ Sfp, ushort* __restrict__ Scomb,
                         ushort* __restrict__ Wg0t, ushort* __restrict__ Wc0t,
                         ushort* __restrict__ Wg1t, ushort* __restrict__ Wc1t,
                         float* __restrict__ h0, float* __restrict__ h1,
                         ushort* __restrict__ matsL0, ushort* __restrict__ matsL1){
  int bx = blockIdx.x, t = threadIdx.x;
  if (bx < NN){                       // init task: node bx
    int n = bx, b = t & 63, cq = t >> 6;
    #pragma unroll
    for (int ii = 0; ii < 16; ++ii){
      int c = cq*16 + ii;
      float h0v = init[(size_t)(b*NN + n)*64 + c];
      float h1v = init[(size_t)BB*NN*64 + (size_t)(b*NN + n)*64 + c];
      h0[(size_t)n*NODE + c*64 + b] = h0v;
      h1[(size_t)n*NODE + c*64 + b] = h1v;
      matsL0[((size_t)(1 + c)*NN + n)*64 + b]  = f2bf(h0v);
      matsL1[((size_t)c*NN + n)*64 + b]        = f2bf(h0v);
      matsL1[((size_t)(64 + c)*NN + n)*64 + b] = f2bf(h1v);
    }
    if (t < 64)
      matsL0[(size_t)n*64 + t] = f2bf(inp[(size_t)t*NN + n]);
  }
  for (int idx = bx*256 + t; idx < 2*NN*NN; idx += SB2*256){
    int s = idx / (NN*NN), rem = idx - s*(NN*NN);
    int i = rem / NN, j = rem - i*NN;
    float v = s ? adj[i*NN + j]/cs[j] : adj[j*NN + i]/rs[j];
    Sfp[idx] = v;
    Scomb[(size_t)(2*s)*NPADR*KD + (size_t)i*KD + j] = f2bf(v);
  }
  // Wt[o][k], k = m*C + c, from W[(c*5+m)*O + o]; zero for k >= 5C
  {
    const float* Ws[4] = { Wg0, Wc0, Wg1, Wc1 };
    ushort* Wts[4]     = { Wg0t, Wc0t, Wg1t, Wc1t };
    const int Cs[4] = { 65, 65, 128, 128 };
    const int Os[4] = { 128, 64, 128, 64 };
    const int Kp[4] = { KP0, KP0, KP1, KP1 };
    for (int q = 0; q < 4; ++q){
      int total = Os[q]*Kp[q];
      for (int idx = bx*256 + t; idx < total; idx += SB2*256){
        int o = idx / Kp[q], k = idx - o*Kp[q];
        int m = k / Cs[q], c = k - m*Cs[q];
        Wts[q][idx] = f2bf(m < 5 ? Ws[q][(c*5 + m)*Os[q] + o] : 0.f);
      }
    }
  }
}

// Scomb slots 1,3 = 2*S_s^2 - I via MFMA (A = Scomb slot 2s bf16, X staged from Sfp)
__global__ __launch_bounds__(256) void k_s2(const float* __restrict__ Sfp,
                                            ushort* __restrict__ Scomb){
  __shared__ ushort X[64][XP];
  int jt = blockIdx.x, rh2 = blockIdx.y, s = blockIdx.z;
  int t = threadIdx.x, w = t >> 6, r = t & 15, g = (t >> 4) & 3;
  const float* S = Sfp + (size_t)s*NN*NN;
  for (int idx = t; idx < KD*8; idx += 256){
    int k = idx >> 3, j0 = (idx & 7)*8;
    #pragma unroll
    for (int i = 0; i < 8; ++i){
      int j = j0 + i, col = jt*64 + j;
      float v = (k < NN && col < NN) ? S[(size_t)k*NN + col] : 0.f;
      X[j][k] = f2bf(v);
    }
  }
  __syncthreads();
  const ushort* A = Scomb + (size_t)(2*s)*NPADR*KD + (size_t)(rh2*192)*KD;
  float4v acc[3][4];
  #pragma unroll
  for (int i = 0; i < 3; ++i)
    #pragma unroll
    for (int q = 0; q < 4; ++q) acc[i][q] = (float4v){0.f,0.f,0.f,0.f};
  for (int kc = 0; kc < KD/32; ++kc){
    short8v a[3], bbv[4];
    #pragma unroll
    for (int mt = 0; mt < 3; ++mt)
      a[mt] = *(const short8v*)&A[(size_t)((w*3 + mt)*16 + r)*KD + kc*32 + g*8];
    #pragma unroll
    for (int nt = 0; nt < 4; ++nt)
      bbv[nt] = *(const short8v*)&X[nt*16 + r][kc*32 + g*8];
    #pragma unroll
    for (int mt = 0; mt < 3; ++mt)
      #pragma unroll
      for (int nt = 0; nt < 4; ++nt)
        acc[mt][nt] = __builtin_amdgcn_mfma_f32_16x16x32_bf16(a[mt], bbv[nt], acc[mt][nt], 0, 0, 0);
  }
  ushort* dst = Scomb + (size_t)(2*s + 1)*NPADR*KD;
  #pragma unroll
  for (int mt = 0; mt < 3; ++mt){
    int node0 = rh2*192 + (w*3 + mt)*16 + g*4;
    #pragma unroll
    for (int nt = 0; nt < 4; ++nt){
      int col = nt*16 + r, jg = jt*64 + col;
      #pragma unroll
      for (int i = 0; i < 4; ++i){
        int n = node0 + i;
        if (n < NN && jg < NN)
          dst[(size_t)n*KD + jg] = f2bf(2.f*acc[mt][nt][i] - (n == jg ? 1.f : 0.f));
      }
    }
  }
}

// ----------------------------------------------- multi-segment diffusion ----
struct Seg {
  const ushort* sm;      // mats source channel base (or null -> sf)
  const float*  sf;      // fp32 [b*NN + n] source (x channel); also writes slot 0
  ushort* dm;  int C,  cs0, cd0;
  ushort* dm2; int C2, cd2;        // optional dual destination (may be null)
};
struct DiffA {
  const ushort* Sc;
  Seg seg[3];
  int e0, e1, nch;       // seg0: [0,e0), seg1: [e0,e1), seg2: [e1,nch)
};

// 1D grid, XCD-aware decomposition: lin = (cu/8)*64 + sub*8 + (cu%8).
// All 8 sub-blocks (y=sub>>2, m=sub&3) of channel cu share lin%8 -> same XCD.
__global__ __launch_bounds__(256, 3) void k_diffN(DiffA da){
  __shared__ ushort X[64][XP];
  ushort (*OB)[OBP] = (ushort (*)[OBP])&X[0][0];   // out-stage overlay
  int lin = blockIdx.x;
  int cu = (lin >> 6)*8 + (lin & 7);
  if (cu >= da.nch) return;
  int sub = (lin >> 3) & 7;
  const int y = sub >> 2, m = sub & 3;
  Seg sg; int u;
  if (cu < da.e0){ sg = da.seg[0]; u = cu; }
  else if (cu < da.e1){ sg = da.seg[1]; u = cu - da.e0; }
  else { sg = da.seg[2]; u = cu - da.e1; }
  int t = threadIdx.x, w = t >> 6;
  int r = t & 15, g = (t >> 4) & 3;

  if (sg.sm){
    // deep-MLP vector stage; swizzled scatter (write conflicts 16-way -> 4-way)
    const ushort* src = sg.sm + (size_t)(sg.cs0 + u)*NN*64;
    int nb = t >> 3, b0 = (t & 7)*8;
    int swz = (t & 3) << 3;                // ((b0+i)>>3)&3 == t&3
    const short8v vz = {0,0,0,0,0,0,0,0};
    short8v v[11];
    #pragma unroll
    for (int j = 0; j < 11; ++j){
      int n = j*32 + nb;
      v[j] = (n < NN) ? *(const short8v*)&src[(size_t)n*64 + b0] : vz;
    }
    #pragma unroll
    for (int j = 0; j < 11; ++j){
      int col = (j*32 + nb) ^ swz;
      #pragma unroll
      for (int i = 0; i < 8; ++i) X[b0 + i][col] = (ushort)v[j][i];
    }
  } else {
    // fp32 x channel: scalar loads + slot-0 writeback; swizzled LDS writes
    for (int j = 0; j < 22; ++j){
      int idx = j*256 + t;                 // 5632 = 64 b * 88 n4-groups
      int b = idx / 88, n4 = (idx - b*88)*4;
      int swz = ((b >> 3) & 3) << 3;
      ushort us[4];
      #pragma unroll
      for (int i = 0; i < 4; ++i)
        us[i] = (n4 + i < NN) ? f2bf(sg.sf[(size_t)b*NN + n4 + i]) : (ushort)0;
      short4v pk; pk[0]=(short)us[0]; pk[1]=(short)us[1]; pk[2]=(short)us[2]; pk[3]=(short)us[3];
      *(short4v*)&X[b][n4 ^ swz] = pk;
      #pragma unroll
      for (int i = 0; i < 4; ++i)
        if (n4 + i < NN) sg.dm[(size_t)(n4 + i)*64 + b] = us[i];
    }
  }
  __syncthreads();

  const ushort* S = da.Sc + ((size_t)m*NPADR + (size_t)y*192)*KD;
  int swr[4];
  #pragma unroll
  for (int nt = 0; nt < 4; ++nt)
    swr[nt] = ((nt*2 + (r >> 3)) & 3) << 3;   // ((nt*16+r)>>3)&3
  float4v acc[3][4];
  #pragma unroll
  for (int i = 0; i < 3; ++i)
    #pragma unroll
    for (int q = 0; q < 4; ++q) acc[i][q] = (float4v){0.f,0.f,0.f,0.f};
  for (int kc = 0; kc < KD/32; ++kc){
    short8v a[3], bbv[4];
    #pragma unroll
    for (int mt = 0; mt < 3; ++mt)
      a[mt] = *(const short8v*)&S[(size_t)((w*3 + mt)*16 + r)*KD + kc*32 + g*8];
    #pragma unroll
    for (int nt = 0; nt < 4; ++nt)
      bbv[nt] = *(const short8v*)&X[nt*16 + r][(kc*32 + g*8) ^ swr[nt]];
    #pragma unroll
    for (int mt = 0; mt < 3; ++mt)
      #pragma unroll
      for (int nt = 0; nt < 4; ++nt)
        acc[mt][nt] = __builtin_amdgcn_mfma_f32_16x16x32_bf16(a[mt], bbv[nt], acc[mt][nt], 0, 0, 0);
  }

  __syncthreads();                        // all waves done reading X -> reuse as OB
  #pragma unroll
  for (int mt = 0; mt < 3; ++mt){
    int lr0 = (w*3 + mt)*16 + g*4;        // local row (within 192-row half)
    #pragma unroll
    for (int nt = 0; nt < 4; ++nt){
      int col = nt*16 + r;
      #pragma unroll
      for (int i = 0; i < 4; ++i)
        OB[lr0 + i][col] = f2bf(acc[mt][nt][i]);
    }
  }
  __syncthreads();
  // coalesced copy-out: full 128B lines (8 lanes x 16B per row); dual dest
  {
    ushort* dst = sg.dm + (size_t)((1 + m)*sg.C + sg.cd0 + u)*NN*64;
    ushort* dst2 = sg.dm2 ? sg.dm2 + (size_t)((1 + m)*sg.C2 + sg.cd2 + u)*NN*64
                          : nullptr;
    int n0 = y*192;
    int lr = t >> 3, q = (t & 7)*8;
    #pragma unroll
    for (int it = 0; it < 6; ++it){
      int row = it*32 + lr;
      int n = n0 + row;
      if (n < NN){
        short8v vv = *(short8v*)&OB[row][q];
        *(short8v*)&dst[(size_t)n*64 + q] = vv;
        if (dst2) *(short8v*)&dst2[(size_t)n*64 + q] = vv;
      }
    }
  }
}

// ------------------------------------------- dual-descriptor W-GEMM (MFMA) ----
struct WgD {
  const ushort* mats; const ushort* Wt; const float* bias;
  float* h; float* uu;
  ushort* dstA; ushort* dstB;         // kk-major slot bases (dstB may be null)
  const float* Wfc; const float* bfc; float* outp;
  int KPAD; int MODE;      // MODE 0: gate (o-tile = oy*64); 1: cand (h-update)
};

template<int KPAD>
static __device__ __forceinline__ void wg_body(
    const WgD& d, int n, int oy, ushort (*XT)[XP], float* fcbuf)
{
  constexpr int NST = (KPAD > 352) ? 2 : 1;
  constexpr int KH  = (KPAD > 352) ? 320 : KPAD;
  constexpr int NCH = KH/32;
  int t = threadIdx.x, w = t >> 6;
  int r = t & 15, g = (t >> 4) & 3;
  const bool fc = (d.MODE == 1) && (d.outp != nullptr);
  if (fc && t < 64) fcbuf[t] = 0.f;

  float4v acc[4];
  #pragma unroll
  for (int nt = 0; nt < 4; ++nt) acc[nt] = (float4v){0.f,0.f,0.f,0.f};

  int kk0 = t >> 3, b0 = (t & 7)*8;
  int swz = (t & 3) << 3;
  int swr[4];
  #pragma unroll
  for (int nt = 0; nt < 4; ++nt)
    swr[nt] = ((nt*2 + (r >> 3)) & 3) << 3;
  #pragma unroll
  for (int st = 0; st < NST; ++st){
    int kbase = st*KH;
    if (st) __syncthreads();
    short8v v[NCH];
    #pragma unroll
    for (int j = 0; j < NCH; ++j)
      v[j] = *(const short8v*)&d.mats[((size_t)(kbase + j*32 + kk0)*NN + n)*64 + b0];
    #pragma unroll
    for (int j = 0; j < NCH; ++j){
      int col = (j*32 + kk0) ^ swz;
      #pragma unroll
      for (int i = 0; i < 8; ++i) XT[b0 + i][col] = (ushort)v[j][i];
    }
    __syncthreads();
    for (int kc = 0; kc < NCH; ++kc){
      short8v a0 = *(const short8v*)&d.Wt[(size_t)(oy*64 + w*16 + r)*KPAD + kbase + kc*32 + g*8];
      short8v bbv[4];
      #pragma unroll
      for (int nt = 0; nt < 4; ++nt)
        bbv[nt] = *(const short8v*)&XT[nt*16 + r][(kc*32 + g*8) ^ swr[nt]];
      #pragma unroll
      for (int nt = 0; nt < 4; ++nt)
        acc[nt] = __builtin_amdgcn_mfma_f32_16x16x32_bf16(a0, bbv[nt], acc[nt], 0, 0, 0);
    }
  }

  __syncthreads();                        // all XT reads done; reuse as out stage
  #pragma unroll
  for (int nt = 0; nt < 4; ++nt){
    int b2 = nt*16 + r;
    float p = 0.f;
    #pragma unroll
    for (int i = 0; i < 4; ++i){
      int o = w*16 + g*4 + i;             // within o-tile
      float vv = acc[nt][i] + d.bias[oy*64 + o];
      if (d.MODE == 0){
        float sg = 1.f/(1.f + expf(-vv));
        if (oy == 0) XT[o][b2] = f2bf(sg * d.h[(size_t)n*NODE + o*64 + b2]);
        else         d.uu[(size_t)n*NODE + o*64 + b2] = sg;
      } else {
        float cv = tanhf(vv);
        size_t idx = (size_t)n*NODE + o*64 + b2;
        float uv = d.uu[idx];
        float hn = uv*d.h[idx] + (1.f - uv)*cv;
        d.h[idx] = hn;
        XT[o][b2] = f2bf(hn);
        if (fc) p += hn * d.Wfc[o];
      }
    }
    if (fc) atomicAdd(&fcbuf[b2], p);
  }
  __syncthreads();
  if (d.MODE == 1 || oy == 0){             // coalesced copy-out of 64 kk-lines
    int o = t >> 2, q = (t & 3)*16;
    short8v v0 = *(short8v*)&XT[o][q];
    short8v v1 = *(short8v*)&XT[o][q + 8];
    ushort* dl = d.dstA + ((size_t)o*NN + n)*64 + q;
    *(short8v*)&dl[0] = v0;
    *(short8v*)&dl[8] = v1;
    if (d.dstB){
      ushort* dl2 = d.dstB + ((size_t)o*NN + n)*64 + q;
      *(short8v*)&dl2[0] = v0;
      *(short8v*)&dl2[8] = v1;
    }
  }
  if (fc && t < 64)
    d.outp[(size_t)t*NN + n] = fcbuf[t] + d.bfc[0];
}

__global__ __launch_bounds__(256) void k_wg2(WgD d0, int n0, WgD d1){
  __shared__ ushort XT[64][XP];
  __shared__ float fcbuf[64];
  const bool first = (blockIdx.x < (unsigned)n0);
  WgD d = first ? d0 : d1;
  int n = first ? blockIdx.x : blockIdx.x - n0;
  int oy = blockIdx.y;
  if (d.MODE == 1 && oy) return;           // block-uniform early exit
  if (d.KPAD == 352) wg_body<352>(d, n, oy, XT, fcbuf);
  else               wg_body<640>(d, n, oy, XT, fcbuf);
}

// ----------------------------------------------------------------- host ----
extern "C" void kernel_launch(void* const* d_in, const int* in_sizes, int n_in,
                              void* d_out, int out_size, void* d_ws, size_t ws_size,
                              hipStream_t stream){
  const float* inp  = (const float*)d_in[0];
  const float* init = (const float*)d_in[1];
  const float* adj  = (const float*)d_in[2];
  const float* Wg0  = (const float*)d_in[3];
  const float* bg0  = (const float*)d_in[4];
  const float* Wc0  = (const float*)d_in[5];
  const float* bc0  = (const float*)d_in[6];
  const float* Wg1  = (const float*)d_in[7];
  const float* bg1  = (const float*)d_in[8];
  const float* Wc1  = (const float*)d_in[9];
  const float* bc1  = (const float*)d_in[10];
  const float* Wfc  = (const float*)d_in[11];
  const float* bfc  = (const float*)d_in[12];
  (void)in_sizes; (void)n_in; (void)out_size; (void)ws_size;

  char* p = (char*)d_ws;
  auto alloc = [&](size_t bytes) -> void* {
    void* q = (void*)p; p += (bytes + 255) & ~(size_t)255; return q;
  };
  ushort* Scomb  = (ushort*)alloc((size_t)4*NPADR*KD*2);
  float*  Sfp    = (float*)alloc((size_t)2*NN*NN*4);
  ushort* Wg0t   = (ushort*)alloc((size_t)128*KP0*2);
  ushort* Wc0t   = (ushort*)alloc((size_t)64*KP0*2);
  ushort* Wg1t   = (ushort*)alloc((size_t)128*KP1*2);
  ushort* Wc1t   = (ushort*)alloc((size_t)64*KP1*2);
  float*  rs     = (float*)alloc(512*4);
  float*  cs     = (float*)alloc(512*4);
  float*  h0     = (float*)alloc((size_t)NN*NODE*4);
  float*  h1     = (float*)alloc((size_t)NN*NODE*4);
  float*  uu0    = (float*)alloc((size_t)NN*NODE*4);
  float*  uu1    = (float*)alloc((size_t)NN*NODE*4);
  ushort* matsL0 = (ushort*)alloc((size_t)KP0*NN*64*2);
  ushort* matsL1 = (ushort*)alloc((size_t)KP1*NN*64*2);
  float* out = (float*)d_out;

  hipMemsetAsync(out, 0, (size_t)BB*NN*4, stream);
  hipMemsetAsync(matsL0 + (size_t)325*NN*64, 0, (size_t)(KP0 - 325)*NN*64*2, stream);
  hipMemsetAsync(Scomb, 0, (size_t)4*NPADR*KD*2, stream);

  k_sums<<<NN, 256, 0, stream>>>(adj, rs, cs);
  k_setup2<<<SB2, 256, 0, stream>>>(adj, rs, cs, inp, init, Wg0, Wc0, Wg1, Wc1,
                                    Sfp, Scomb, Wg0t, Wc0t, Wg1t, Wc1t,
                                    h0, h1, matsL0, matsL1);
  k_s2<<<dim3(6, 2, 2), 256, 0, stream>>>(Sfp, Scomb);

  auto diffGrid = [](int nch){ return ((nch + 7)/8)*64; };

  // segments (h0 diffusion dual-written into matsL0 AND matsL1)
  Seg segH0d = { matsL0, nullptr, matsL0, 65, 1, 1, matsL1, 128, 0 };   // 64 ch
  Seg segH1  = { matsL1, nullptr, matsL1, 128, 64, 64, nullptr, 0, 0 }; // 64 ch
  Seg segRh0 = { matsL0, nullptr, matsL0, 65, 1, 1, nullptr, 0, 0 };    // 64 ch
  Seg segRh1 = { matsL1, nullptr, matsL1, 128, 64, 64, nullptr, 0, 0 }; // 64 ch

  WgD wg_g0 = { matsL0, Wg0t, bg0, h0, uu0, matsL0 + (size_t)1*NN*64, nullptr,
                nullptr, nullptr, nullptr, KP0, 0 };
  WgD wg_c0 = { matsL0, Wc0t, bc0, h0, uu0, matsL0 + (size_t)1*NN*64, matsL1,
                nullptr, nullptr, nullptr, KP0, 1 };
  WgD wg_g1 = { matsL1, Wg1t, bg1, h1, uu1, matsL1 + (size_t)64*NN*64, nullptr,
                nullptr, nullptr, nullptr, KP1, 0 };

  for (int t = 0; t <= TT; ++t){
    // ---- A(t): diff [h0_t dual | h1_{t-1} | x_t] ----
    if (t < TT){
      Seg segX = { nullptr, inp + (size_t)t*BB*NN, matsL0, 65, 0, 0, nullptr, 0, 0 };
      DiffA da = { Scomb, { segH0d, segH1, segX }, 64, 128, 129 };
      k_diffN<<<diffGrid(129), 256, 0, stream>>>(da);
    } else {
      DiffA da = { Scomb, { segH0d, segH1, segH1 }, 64, 128, 128 };
      k_diffN<<<diffGrid(128), 256, 0, stream>>>(da);
    }
    // ---- B(t): wg [L0-gate(t) | L1-gate(t-1)] ----
    if (t == 0)
      k_wg2<<<dim3(NN, 2), 256, 0, stream>>>(wg_g0, NN, wg_g0);
    else if (t < TT)
      k_wg2<<<dim3(2*NN, 2), 256, 0, stream>>>(wg_g0, NN, wg_g1);
    else
      k_wg2<<<dim3(NN, 2), 256, 0, stream>>>(wg_g1, NN, wg_g1);
    // ---- C(t): diff [rh0(t) | rh1(t-1)] ----
    if (t == 0){
      DiffA da = { Scomb, { segRh0, segRh0, segRh0 }, 64, 64, 64 };
      k_diffN<<<diffGrid(64), 256, 0, stream>>>(da);
    } else if (t < TT){
      DiffA da = { Scomb, { segRh0, segRh1, segRh1 }, 64, 128, 128 };
      k_diffN<<<diffGrid(128), 256, 0, stream>>>(da);
    } else {
      DiffA da = { Scomb, { segRh1, segRh1, segRh1 }, 64, 64, 64 };
      k_diffN<<<diffGrid(64), 256, 0, stream>>>(da);
    }
    // ---- D(t): wg [L0-cand(t) | L1-cand(t-1) + fc -> out[t]] ----
    WgD wg_c1 = { matsL1, Wc1t, bc1, h1, uu1, matsL1 + (size_t)64*NN*64, nullptr,
                  Wfc, bfc, out + (size_t)t*BB*NN, KP1, 1 };
    if (t == 0)
      k_wg2<<<dim3(NN, 1), 256, 0, stream>>>(wg_c0, NN, wg_c0);
    else if (t < TT)
      k_wg2<<<dim3(2*NN, 1), 256, 0, stream>>>(wg_c0, NN, wg_c1);
    else
      k_wg2<<<dim3(NN, 1), 256, 0, stream>>>(wg_c1, NN, wg_c1);
  }
}